// Round 1
// baseline (743.501 us; speedup 1.0000x reference)
//
#include <hip/hip_runtime.h>
#include <math.h>

// Problem dims (fixed by setup_inputs): channel dims are compile-time; N/E passed at runtime.
#define D128 128   // H*Ch
#define CH32 32
#define CE16 16

static __device__ __forceinline__ float red32(float t) {
    t += __shfl_xor(t, 1);
    t += __shfl_xor(t, 2);
    t += __shfl_xor(t, 4);
    t += __shfl_xor(t, 8);
    t += __shfl_xor(t, 16);
    return t;
}

// ---------------- CSR build ----------------
__global__ void k_hist(const int* __restrict__ dst, int* __restrict__ deg, int E) {
    int e = blockIdx.x * blockDim.x + threadIdx.x;
    if (e < E) atomicAdd(&deg[dst[e]], 1);
}

__global__ void k_scan1(const int* __restrict__ deg, int* __restrict__ offs,
                        int* __restrict__ bsum, int N) {
    __shared__ int buf[256];
    int t = threadIdx.x;
    int i = blockIdx.x * 256 + t;
    int v = (i < N) ? deg[i] : 0;
    buf[t] = v;
    __syncthreads();
    #pragma unroll
    for (int off = 1; off < 256; off <<= 1) {
        int val = (t >= off) ? buf[t - off] : 0;
        __syncthreads();
        buf[t] += val;
        __syncthreads();
    }
    if (i < N) offs[i] = buf[t] - v;          // exclusive within block
    if (t == 255) bsum[blockIdx.x] = buf[255]; // block total
}

__global__ void k_scan2(const int* __restrict__ bsum, int* __restrict__ boff, int nb) {
    // requires nb <= 256 (N <= 65536)
    __shared__ int buf[256];
    int t = threadIdx.x;
    int v = (t < nb) ? bsum[t] : 0;
    buf[t] = v;
    __syncthreads();
    #pragma unroll
    for (int off = 1; off < 256; off <<= 1) {
        int val = (t >= off) ? buf[t - off] : 0;
        __syncthreads();
        buf[t] += val;
        __syncthreads();
    }
    if (t < nb) boff[t] = buf[t] - v;
}

__global__ void k_scan3(const int* __restrict__ boff, int* __restrict__ offs,
                        int* __restrict__ cur, int N, int E) {
    int i = blockIdx.x * blockDim.x + threadIdx.x;
    if (i < N) {
        int o = offs[i] + boff[i >> 8];
        offs[i] = o;
        cur[i] = o;
    }
    if (i == 0) offs[N] = E;
}

__global__ void k_scatter(const int* __restrict__ src, const int* __restrict__ dst,
                          int* __restrict__ cur, int* __restrict__ csr_src,
                          int* __restrict__ csr_eid, int E) {
    int e = blockIdx.x * blockDim.x + threadIdx.x;
    if (e < E) {
        int d = dst[e];
        int p = atomicAdd(&cur[d], 1);
        csr_src[p] = src[e];
        csr_eid[p] = e;
    }
}

// ---------------- node projection: q,k,v (128 cols) + skip (32 cols) ----------------
__global__ __launch_bounds__(128) void k_nodeproj(
    const float* __restrict__ xin,
    const float* __restrict__ Wq, const float* __restrict__ bq,
    const float* __restrict__ Wk, const float* __restrict__ bk,
    const float* __restrict__ Wv, const float* __restrict__ bv,
    const float* __restrict__ Ws, const float* __restrict__ bs,
    float* __restrict__ q, float* __restrict__ k, float* __restrict__ v,
    float* __restrict__ skip, int N)
{
    int tid = threadIdx.x;      // 0..127: output column of q/k/v
    int c   = tid & 31;         // output column of skip
    float wq[32], wk[32], wv[32], ws[32];
    #pragma unroll
    for (int j = 0; j < 32; j++) {
        wq[j] = Wq[j * D128 + tid];
        wk[j] = Wk[j * D128 + tid];
        wv[j] = Wv[j * D128 + tid];
        ws[j] = Ws[j * CH32 + c];
    }
    float bqc = bq[tid], bkc = bk[tid], bvc = bv[tid], bsc = bs[c];
    __shared__ float xs[4][32];
    int nchunk = (N + 3) / 4;
    for (int chk = blockIdx.x; chk < nchunk; chk += gridDim.x) {
        int base = chk * 4;
        {
            int r = tid >> 5;
            int n = base + r;
            xs[r][c] = (n < N) ? xin[n * 32 + c] : 0.f;
        }
        __syncthreads();
        #pragma unroll
        for (int r = 0; r < 4; r++) {
            int n = base + r;
            if (n < N) {
                float aq = bqc, ak = bkc, av = bvc;
                #pragma unroll
                for (int j = 0; j < 32; j++) {
                    float xj = xs[r][j];
                    aq = fmaf(xj, wq[j], aq);
                    ak = fmaf(xj, wk[j], ak);
                    av = fmaf(xj, wv[j], av);
                }
                q[n * D128 + tid] = aq;
                k[n * D128 + tid] = ak;
                v[n * D128 + tid] = av;
            }
        }
        {   // skip: thread handles node base+(tid>>5), channel c
            int r = tid >> 5;
            int n = base + r;
            if (n < N) {
                float as = bsc;
                #pragma unroll
                for (int j = 0; j < 32; j++) as = fmaf(xs[r][j], ws[j], as);
                skip[n * 32 + c] = as;
            }
        }
        __syncthreads();
    }
}

// ---------------- edge attention: one block (128 thr) per dst node ----------------
__global__ __launch_bounds__(128) void k_edgeattn(
    const float* __restrict__ q, const float* __restrict__ k, const float* __restrict__ v,
    const float* __restrict__ skip,
    const float* __restrict__ ea, const float* __restrict__ We,
    const int* __restrict__ offs, const int* __restrict__ csr_src,
    const int* __restrict__ csr_eid,
    float* __restrict__ hout)
{
    int node = blockIdx.x;
    int tid = threadIdx.x;     // col = h*32 + c
    __shared__ float WeL[16 * D128];
    __shared__ float red[128];
    #pragma unroll
    for (int j = 0; j < 16; j++) WeL[j * D128 + tid] = We[j * D128 + tid];
    __syncthreads();

    float qv = q[node * D128 + tid];
    int s0 = offs[node], s1 = offs[node + 1];
    float m = -INFINITY, l = 0.f, acc = 0.f;
    const float4* ea4 = (const float4*)ea;

    for (int i = s0; i < s1; i++) {
        int sidx = csr_src[i];
        int eid  = csr_eid[i];
        float4 a0 = ea4[eid * 4 + 0];
        float4 a1 = ea4[eid * 4 + 1];
        float4 a2 = ea4[eid * 4 + 2];
        float4 a3 = ea4[eid * 4 + 3];
        float ec;
        ec = a0.x * WeL[0 * D128 + tid];
        ec = fmaf(a0.y, WeL[1  * D128 + tid], ec);
        ec = fmaf(a0.z, WeL[2  * D128 + tid], ec);
        ec = fmaf(a0.w, WeL[3  * D128 + tid], ec);
        ec = fmaf(a1.x, WeL[4  * D128 + tid], ec);
        ec = fmaf(a1.y, WeL[5  * D128 + tid], ec);
        ec = fmaf(a1.z, WeL[6  * D128 + tid], ec);
        ec = fmaf(a1.w, WeL[7  * D128 + tid], ec);
        ec = fmaf(a2.x, WeL[8  * D128 + tid], ec);
        ec = fmaf(a2.y, WeL[9  * D128 + tid], ec);
        ec = fmaf(a2.z, WeL[10 * D128 + tid], ec);
        ec = fmaf(a2.w, WeL[11 * D128 + tid], ec);
        ec = fmaf(a3.x, WeL[12 * D128 + tid], ec);
        ec = fmaf(a3.y, WeL[13 * D128 + tid], ec);
        ec = fmaf(a3.z, WeL[14 * D128 + tid], ec);
        ec = fmaf(a3.w, WeL[15 * D128 + tid], ec);

        float kj = k[sidx * D128 + tid] + ec;
        float vj = v[sidx * D128 + tid] + ec;
        float t = red32(qv * kj);                 // per-head dot over 32 lanes
        float alpha = t * 0.17677669529663687f;   // 1/sqrt(32)
        float mn = fmaxf(m, alpha);
        float p  = __expf(alpha - mn);
        float sc = __expf(m - mn);
        l   = l * sc + p;
        acc = acc * sc + p * vj;
        m = mn;
    }
    float r = acc / (l + 1e-16f);
    red[tid] = r;
    __syncthreads();
    if (tid < 32) {
        float o = 0.25f * (red[tid] + red[tid + 32] + red[tid + 64] + red[tid + 96])
                + skip[node * 32 + tid];
        hout[node * 32 + tid] = fmaxf(o, 0.f);    // relu fused
    }
}

// ---------------- edge MLP: thread per edge ----------------
__global__ __launch_bounds__(256) void k_mlp(
    const float* __restrict__ h, const float* __restrict__ ea,
    const int* __restrict__ src, const int* __restrict__ dst,
    const float* __restrict__ Wm1, const float* __restrict__ bm1,
    const float* __restrict__ Wm2, const float* __restrict__ bm2,
    float* __restrict__ out, int E)
{
    __shared__ float4 W4[80 * 8];     // Wm1 [80][32] as float4 rows
    __shared__ float bm1L[32];
    __shared__ float wm2L[32];
    int tid = threadIdx.x;
    const float4* Wm1_4 = (const float4*)Wm1;
    for (int i = tid; i < 640; i += 256) W4[i] = Wm1_4[i];
    if (tid < 32) { bm1L[tid] = bm1[tid]; wm2L[tid] = Wm2[tid]; }
    __syncthreads();

    int e = blockIdx.x * 256 + tid;
    if (e >= E) return;
    float b2 = bm2[0];
    int s = src[e], d = dst[e];

    float4 acc[8];
    #pragma unroll
    for (int i = 0; i < 8; i++) acc[i] = make_float4(0.f, 0.f, 0.f, 0.f);

    auto dorow = [&](int j, float xj) {
        #pragma unroll
        for (int c4 = 0; c4 < 8; c4++) {
            float4 w = W4[j * 8 + c4];
            acc[c4].x = fmaf(xj, w.x, acc[c4].x);
            acc[c4].y = fmaf(xj, w.y, acc[c4].y);
            acc[c4].z = fmaf(xj, w.z, acc[c4].z);
            acc[c4].w = fmaf(xj, w.w, acc[c4].w);
        }
    };

    const float4* hs  = (const float4*)(h + (size_t)s * 32);
    const float4* hd  = (const float4*)(h + (size_t)d * 32);
    const float4* eav = (const float4*)(ea + (size_t)e * 16);
    #pragma unroll
    for (int qd = 0; qd < 8; qd++) {   // rows 0..31: h[src]
        float4 xv = hs[qd];
        dorow(qd * 4 + 0, xv.x); dorow(qd * 4 + 1, xv.y);
        dorow(qd * 4 + 2, xv.z); dorow(qd * 4 + 3, xv.w);
    }
    #pragma unroll
    for (int qd = 0; qd < 4; qd++) {   // rows 32..47: edge_attr
        float4 xv = eav[qd];
        dorow(32 + qd * 4 + 0, xv.x); dorow(32 + qd * 4 + 1, xv.y);
        dorow(32 + qd * 4 + 2, xv.z); dorow(32 + qd * 4 + 3, xv.w);
    }
    #pragma unroll
    for (int qd = 0; qd < 8; qd++) {   // rows 48..79: h[dst]
        float4 xv = hd[qd];
        dorow(48 + qd * 4 + 0, xv.x); dorow(48 + qd * 4 + 1, xv.y);
        dorow(48 + qd * 4 + 2, xv.z); dorow(48 + qd * 4 + 3, xv.w);
    }

    float y = b2;
    #pragma unroll
    for (int c4 = 0; c4 < 8; c4++) {
        y += fmaxf(acc[c4].x + bm1L[c4 * 4 + 0], 0.f) * wm2L[c4 * 4 + 0];
        y += fmaxf(acc[c4].y + bm1L[c4 * 4 + 1], 0.f) * wm2L[c4 * 4 + 1];
        y += fmaxf(acc[c4].z + bm1L[c4 * 4 + 2], 0.f) * wm2L[c4 * 4 + 2];
        y += fmaxf(acc[c4].w + bm1L[c4 * 4 + 3], 0.f) * wm2L[c4 * 4 + 3];
    }
    out[e] = y;
}

extern "C" void kernel_launch(void* const* d_in, const int* in_sizes, int n_in,
                              void* d_out, int out_size, void* d_ws, size_t ws_size,
                              hipStream_t stream)
{
    const float* x  = (const float*)d_in[0];
    const float* ea = (const float*)d_in[1];
    const int*   ei = (const int*)d_in[2];
    const int N = in_sizes[0] / 32;
    const int E = in_sizes[1] / 16;
    const int* src = ei;
    const int* dst = ei + E;

    const float *Wq1 = (const float*)d_in[3],  *bq1 = (const float*)d_in[4];
    const float *Wk1 = (const float*)d_in[5],  *bk1 = (const float*)d_in[6];
    const float *Wv1 = (const float*)d_in[7],  *bv1 = (const float*)d_in[8];
    const float *We1 = (const float*)d_in[9],  *Ws1 = (const float*)d_in[10];
    const float *bs1 = (const float*)d_in[11];
    const float *Wq2 = (const float*)d_in[12], *bq2 = (const float*)d_in[13];
    const float *Wk2 = (const float*)d_in[14], *bk2 = (const float*)d_in[15];
    const float *Wv2 = (const float*)d_in[16], *bv2 = (const float*)d_in[17];
    const float *We2 = (const float*)d_in[18], *Ws2 = (const float*)d_in[19];
    const float *bs2 = (const float*)d_in[20];
    const float *Wm1 = (const float*)d_in[21], *bm1 = (const float*)d_in[22];
    const float *Wm2 = (const float*)d_in[23], *bm2 = (const float*)d_in[24];

    // workspace carve-out (all 256B-aligned); total ~104 MB
    char* w = (char*)d_ws;
    auto alloc = [&](size_t bytes) -> void* {
        void* p = (void*)w;
        w += (bytes + 255) & ~(size_t)255;
        return p;
    };
    int* deg      = (int*)alloc((size_t)N * 4);
    int* offs     = (int*)alloc(((size_t)N + 1) * 4);
    int* cur      = (int*)alloc((size_t)N * 4);
    int* bsum     = (int*)alloc(256 * 4);
    int* boff     = (int*)alloc(256 * 4);
    int* csr_src  = (int*)alloc((size_t)E * 4);
    int* csr_eid  = (int*)alloc((size_t)E * 4);
    float* qb     = (float*)alloc((size_t)N * 128 * 4);
    float* kb     = (float*)alloc((size_t)N * 128 * 4);
    float* vb     = (float*)alloc((size_t)N * 128 * 4);
    float* skipb  = (float*)alloc((size_t)N * 32 * 4);
    float* h1     = (float*)alloc((size_t)N * 32 * 4);
    float* h2     = (float*)alloc((size_t)N * 32 * 4);

    hipMemsetAsync(deg, 0, (size_t)N * 4, stream);

    int ebl = (E + 255) / 256;
    int nb  = (N + 255) / 256;   // 196 <= 256, required by k_scan2
    k_hist<<<ebl, 256, 0, stream>>>(dst, deg, E);
    k_scan1<<<nb, 256, 0, stream>>>(deg, offs, bsum, N);
    k_scan2<<<1, 256, 0, stream>>>(bsum, boff, nb);
    k_scan3<<<nb, 256, 0, stream>>>(boff, offs, cur, N, E);
    k_scatter<<<ebl, 256, 0, stream>>>(src, dst, cur, csr_src, csr_eid, E);

    // layer 1
    k_nodeproj<<<512, 128, 0, stream>>>(x, Wq1, bq1, Wk1, bk1, Wv1, bv1, Ws1, bs1,
                                        qb, kb, vb, skipb, N);
    k_edgeattn<<<N, 128, 0, stream>>>(qb, kb, vb, skipb, ea, We1,
                                      offs, csr_src, csr_eid, h1);
    // layer 2
    k_nodeproj<<<512, 128, 0, stream>>>(h1, Wq2, bq2, Wk2, bk2, Wv2, bv2, Ws2, bs2,
                                        qb, kb, vb, skipb, N);
    k_edgeattn<<<N, 128, 0, stream>>>(qb, kb, vb, skipb, ea, We2,
                                      offs, csr_src, csr_eid, h2);
    // edge MLP
    k_mlp<<<ebl, 256, 0, stream>>>(h2, ea, src, dst, Wm1, bm1, Wm2, bm2,
                                   (float*)d_out, E);
}